// Round 1
// baseline (68.725 us; speedup 1.0000x reference)
//
#include <hip/hip_runtime.h>

// PatchQuantumGenerator, round 6: split into (1) a tiny 4-block kernel that
// builds the four M_g = P*U matrices once and emits f16 MFMA A-fragments to
// workspace, and (2) a batch GEMM kernel where each block handles ALL 4
// generators for 128 batches (sincos staged once, B-frag built once, 8 MFMAs
// per 16-batch tile). Removes the per-block 28-barrier M build and the 4x
// redundant x read/sincos of the previous fused kernel.

#define NGEN 4
#define NLAY 4
#define NQ   5

typedef _Float16 half8 __attribute__((ext_vector_type(8)));
typedef float    f32x4 __attribute__((ext_vector_type(4)));

// ---------------------------------------------------------------------------
// Kernel 1: build M_g (16x32 complex) by row propagation in LDS, gates
// right-multiplied in reverse circuit order (verified r1-r5). One block per g.
// Emits A-fragments: element (m,k) -> lane L=(k>>3)*16+m, reg k&7, as
// ws[g*1024 + L*8 + jj] (real) and ws[g*1024 + 512 + L*8 + jj] (imag).
// ---------------------------------------------------------------------------
__global__ __launch_bounds__(256) void pqg_build(
    const float* __restrict__ wts,    // [4,4,5,3]
    _Float16* __restrict__ ws)        // [4][2][512] f16 A-fragments
{
    __shared__ float gm[NLAY * NQ * 8];
    __shared__ float Mr[16 * 33];
    __shared__ float Mi[16 * 33];

    const int t = threadIdx.x;
    const int g = blockIdx.x;

    // Gate matrices (Rot = RZ(omega) RY(theta) RZ(phi)).
    if (t < NLAY * NQ) {
        const float* wp = wts + (g * (NLAY * NQ) + t) * 3;
        const float phi = wp[0], theta = wp[1], omega = wp[2];
        const float a = 0.5f * (phi + omega);
        const float bb = 0.5f * (phi - omega);
        const float h = 0.5f * theta;
        const float sa = __sinf(a), ca = __cosf(a);
        const float sb = __sinf(bb), cb = __cosf(bb);
        const float st = __sinf(h), ct = __cosf(h);
        float* m = &gm[t * 8];
        m[0] =  ca * ct;  m[1] = -sa * ct;   // u00
        m[2] = -cb * st;  m[3] = -sb * st;   // u01
        m[4] =  cb * st;  m[5] = -sb * st;   // u10
        m[6] =  ca * ct;  m[7] =  sa * ct;   // u11
    }

    // M init: M = P (rows 0..15 of identity), stride 33.
#pragma unroll
    for (int h = 0; h < 2; ++h) {
        const int idx = h * 256 + t;          // 0..511
        const int r = idx >> 5, c = idx & 31;
        Mr[r * 33 + c] = (r == c) ? 1.0f : 0.0f;
        Mi[r * 33 + c] = 0.0f;
    }
    __syncthreads();

    const int row = t & 15;
    const int p   = t >> 4;                   // 0..15

#pragma clang loop unroll(disable)
    for (int l = NLAY - 1; l >= 0; --l) {
        // CNOT group of layer l (processed first in reverse order).
        {
            const int c0 = p, c1 = p + 16;
            int v0 = c0, v1 = c1;
#pragma unroll
            for (int q = 0; q < NQ; ++q) {
                const int cb = 16 >> q;
                int tq = q + l + 1; if (tq >= NQ) tq -= NQ;
                const int tb = 16 >> tq;
                if (v0 & cb) v0 ^= tb;
                if (v1 & cb) v1 ^= tb;
            }
            const float a0r = Mr[row * 33 + v0], a0i = Mi[row * 33 + v0];
            const float a1r = Mr[row * 33 + v1], a1i = Mi[row * 33 + v1];
            __syncthreads();
            Mr[row * 33 + c0] = a0r;  Mi[row * 33 + c0] = a0i;
            Mr[row * 33 + c1] = a1r;  Mi[row * 33 + c1] = a1i;
            __syncthreads();
        }
        // Rot gates of layer l, reverse order q=4..0.
#pragma clang loop unroll(disable)
        for (int q = NQ - 1; q >= 0; --q) {
            const float* m = &gm[(l * NQ + q) * 8];
            const float u00r = m[0], u00i = m[1], u01r = m[2], u01i = m[3];
            const float u10r = m[4], u10i = m[5], u11r = m[6], u11i = m[7];
            const int sb = 16 >> q;
            const int lowm = sb - 1;
            const int i = ((p & ~lowm) << 1) | (p & lowm);
            const int j = i | sb;
            const int ii = row * 33 + i, jj = row * 33 + j;
            const float ar = Mr[ii], ai = Mi[ii];
            const float br = Mr[jj], bi = Mi[jj];
            Mr[ii] = u00r * ar - u00i * ai + u10r * br - u10i * bi;
            Mi[ii] = u00r * ai + u00i * ar + u10r * bi + u10i * br;
            Mr[jj] = u01r * ar - u01i * ai + u11r * br - u11i * bi;
            Mi[jj] = u01r * ai + u01i * ar + u11r * bi + u11i * br;
            __syncthreads();
        }
    }

    // Emit f16 A-fragments to workspace.
#pragma unroll
    for (int h = 0; h < 2; ++h) {
        const int idx = h * 256 + t;          // 0..511
        const int k = idx >> 4, m = idx & 15;
        const int L = (k >> 3) * 16 + m;
        const int jj = k & 7;
        ws[g * 1024 + L * 8 + jj]       = (_Float16)Mr[m * 33 + k];
        ws[g * 1024 + 512 + L * 8 + jj] = (_Float16)Mi[m * 33 + k];
    }
}

// ---------------------------------------------------------------------------
// Kernel 2: per block, 128 batches x ALL 4 generators. Stage sincos once,
// each wave holds the 4 g A-fragments in VGPRs, 2 tiles of 16 batches per
// wave, 8 MFMAs (4g x R/I) per tile. Epilogue identical to verified r5.
// ---------------------------------------------------------------------------
#define BPB 128

__global__ __launch_bounds__(256) void pqg_gemm(
    const float* __restrict__ x,              // [B,5]
    const _Float16* __restrict__ wsH,         // [4][2][512]
    float* __restrict__ out)                  // [B,64]
{
    __shared__ float scC[BPB * 5];
    __shared__ float scS[BPB * 5];

    const int t  = threadIdx.x;
    const int b0 = blockIdx.x * BPB;

    // Stage sincos: 128*5 = 640 floats = 160 float4 (b0*5*4 = 2560B aligned).
    if (t < 160) {
        const float4 v = ((const float4*)(x + (size_t)b0 * 5))[t];
        scS[4 * t + 0] = __sinf(0.5f * v.x);  scC[4 * t + 0] = __cosf(0.5f * v.x);
        scS[4 * t + 1] = __sinf(0.5f * v.y);  scC[4 * t + 1] = __cosf(0.5f * v.y);
        scS[4 * t + 2] = __sinf(0.5f * v.z);  scC[4 * t + 2] = __cosf(0.5f * v.z);
        scS[4 * t + 3] = __sinf(0.5f * v.w);  scC[4 * t + 3] = __cosf(0.5f * v.w);
    }

    const int lane = t & 63;
    const int wv   = t >> 6;
    const int quad = lane >> 4;
    const int n    = lane & 15;

    // A-fragments for all 4 g (L2-resident after first touch): 32 VGPRs.
    half8 Ar[NGEN], Ai[NGEN];
#pragma unroll
    for (int g = 0; g < NGEN; ++g) {
        Ar[g] = *(const half8*)&wsH[g * 1024 + lane * 8];
        Ai[g] = *(const half8*)&wsH[g * 1024 + 512 + lane * 8];
    }
    __syncthreads();

#pragma unroll
    for (int tt = 0; tt < 2; ++tt) {
        const int bl = wv * 32 + tt * 16 + n;
        const int b  = b0 + bl;
        const float* C = &scC[bl * 5];
        const float* S = &scS[bl * 5];

        // B-frag bit-map (verified r2): k=quad*8+j; quad&2->q0, quad&1->q1,
        // j&4->q2, j&2->q3, j&1->q4.
        const float f01 = ((quad & 2) ? S[0] : C[0]) * ((quad & 1) ? S[1] : C[1]);
        const float a0 = f01 * C[2], a1 = f01 * S[2];
        const float b00 = a0 * C[3], b01 = a0 * S[3];
        const float b10 = a1 * C[3], b11 = a1 * S[3];

        half8 Bf;
        Bf[0] = (_Float16)(b00 * C[4]);  Bf[1] = (_Float16)(b00 * S[4]);
        Bf[2] = (_Float16)(b01 * C[4]);  Bf[3] = (_Float16)(b01 * S[4]);
        Bf[4] = (_Float16)(b10 * C[4]);  Bf[5] = (_Float16)(b10 * S[4]);
        Bf[6] = (_Float16)(b11 * C[4]);  Bf[7] = (_Float16)(b11 * S[4]);

#pragma unroll
        for (int g = 0; g < NGEN; ++g) {
            f32x4 accR = {0.f, 0.f, 0.f, 0.f};
            f32x4 accI = {0.f, 0.f, 0.f, 0.f};
            accR = __builtin_amdgcn_mfma_f32_16x16x32_f16(Ar[g], Bf, accR, 0, 0, 0);
            accI = __builtin_amdgcn_mfma_f32_16x16x32_f16(Ai[g], Bf, accI, 0, 0, 0);

            // C/D: col = lane&15 (batch), row = quad*4 + reg (output k).
            const float p0 = accR[0] * accR[0] + accI[0] * accI[0];
            const float p1 = accR[1] * accR[1] + accI[1] * accI[1];
            const float p2 = accR[2] * accR[2] + accI[2] * accI[2];
            const float p3 = accR[3] * accR[3] + accI[3] * accI[3];

            float mx = fmaxf(fmaxf(p0, p1), fmaxf(p2, p3));
            mx = fmaxf(mx, __shfl_xor(mx, 16));
            mx = fmaxf(mx, __shfl_xor(mx, 32));
            const float inv = 1.0f / mx;

            const float4 o = make_float4(p0 * inv, p1 * inv, p2 * inv, p3 * inv);
            *(float4*)(out + (size_t)b * 64 + g * 16 + quad * 4) = o;
        }
    }
}

extern "C" void kernel_launch(void* const* d_in, const int* in_sizes, int n_in,
                              void* d_out, int out_size, void* d_ws, size_t ws_size,
                              hipStream_t stream) {
    const float* x = (const float*)d_in[0];   // [B, 5]
    const float* w = (const float*)d_in[1];   // [4, 4, 5, 3]
    float* out = (float*)d_out;               // [B, 64]
    _Float16* ws = (_Float16*)d_ws;           // 8 KB used
    const int B = in_sizes[0] / NQ;           // 65536

    pqg_build<<<NGEN, 256, 0, stream>>>(w, ws);
    pqg_gemm<<<B / BPB, 256, 0, stream>>>(x, ws, out);
}